// Round 1
// baseline (131.803 us; speedup 1.0000x reference)
//
#include <hip/hip_runtime.h>

#define HW1 16384   // 128*128
#define HW2 4096    // 64*64
#define HW3 1024    // 32*32
#define NB  4
#define NCH 256

__device__ inline float4 f4add(float4 a, float4 b) {
    a.x += b.x; a.y += b.y; a.z += b.z; a.w += b.w; return a;
}

// clamp-to-edge half-pixel bilinear sample of an n x n map at output coord (y,x)
// src coordinate = coord*scl - off   (scl=0.5,off=0.25 for 2x; scl=0.25,off=0.375 for 4x)
__device__ inline float bil(const float* m, int n, int y, int x, float scl, float off) {
    float fy = y * scl - off, fx = x * scl - off;
    float fy0 = floorf(fy), fx0 = floorf(fx);
    float wy = fy - fy0, wx = fx - fx0;
    int y0 = max((int)fy0, 0), y1 = min((int)fy0 + 1, n - 1);
    int x0 = max((int)fx0, 0), x1 = min((int)fx0 + 1, n - 1);
    float a = m[y0 * n + x0] * (1.f - wx) + m[y0 * n + x1] * wx;
    float b = m[y1 * n + x0] * (1.f - wx) + m[y1 * n + x1] * wx;
    return a * (1.f - wy) + b * wy;
}

// Channel sums of t0_l1 (128x128), t0_l2 (64x64), t0_l3 (32x32).
// Block = 256 threads = 8 channel-slices x 32 pixel-groups (float4).
__global__ __launch_bounds__(256) void k_sums(
    const float* __restrict__ l1, const float* __restrict__ l2, const float* __restrict__ l3,
    float* __restrict__ SUM1, float* __restrict__ S2, float* __restrict__ S3) {
    __shared__ float4 red[256];
    int t = threadIdx.x, s = t >> 5, g = t & 31;
    int blk = blockIdx.x;
    const float* src; float* dst; int hw; int gg;
    if (blk < 512) {              // L1: 16384 float4-groups
        gg = blk * 32 + g; int p4 = gg * 4;
        int b = p4 >> 14, off = p4 & (HW1 - 1);
        src = l1 + ((size_t)(b * NCH + s * 32)) * HW1 + off; dst = SUM1; hw = HW1;
    } else if (blk < 640) {       // L2: 4096 groups
        gg = (blk - 512) * 32 + g; int p4 = gg * 4;
        int b = p4 >> 12, off = p4 & (HW2 - 1);
        src = l2 + ((size_t)(b * NCH + s * 32)) * HW2 + off; dst = S2; hw = HW2;
    } else {                      // L3: 1024 groups
        gg = (blk - 640) * 32 + g; int p4 = gg * 4;
        int b = p4 >> 10, off = p4 & (HW3 - 1);
        src = l3 + ((size_t)(b * NCH + s * 32)) * HW3 + off; dst = S3; hw = HW3;
    }
    float4 acc = make_float4(0.f, 0.f, 0.f, 0.f);
    #pragma unroll 8
    for (int c = 0; c < 32; ++c)
        acc = f4add(acc, *(const float4*)(src + (size_t)c * hw));
    red[t] = acc;
    __syncthreads();
    if (s < 4) red[t] = f4add(red[t], red[t + 128]);
    __syncthreads();
    if (s < 2) red[t] = f4add(red[t], red[t + 64]);
    __syncthreads();
    if (s == 0) {
        float4 r = f4add(red[t], red[t + 32]);
        ((float4*)dst)[gg] = r;
    }
}

// One block per output row n = b'*64 + q' (n in [0,256)).
// Patch source: b = n % 4, qp = n / 4 (the reference's transpose+reshape shuffle).
__global__ __launch_bounds__(128) void k_query(
    const float* __restrict__ SUM1, const float* __restrict__ S2, const float* __restrict__ S3,
    const float* __restrict__ qb,
    const float* __restrict__ ow1, const float* __restrict__ ob1,
    const float* __restrict__ ow2, const float* __restrict__ ob2,
    const float* __restrict__ sw1, const float* __restrict__ sb1,
    const float* __restrict__ sw2, const float* __restrict__ sb2,
    int* __restrict__ RS, int* __restrict__ CS, float* __restrict__ SC) {
    __shared__ float feat[256];
    __shared__ float ho[128], hs[128];
    __shared__ float res[3];
    int n = blockIdx.x, t = threadIdx.x;
    int b = n & 3, qp = n >> 2;
    int qi = qp >> 3, qj = qp & 7;
    const float* S2b = S2 + b * HW2;
    const float* S3b = S3 + b * HW3;
    for (int d = t; d < 256; d += 128) {
        int i = d >> 4, j = d & 15;
        int y = 16 * qi + i, x = 16 * qj + j;
        float v = SUM1[b * HW1 + y * 128 + x];
        v += bil(S2b, 64, y, x, 0.5f, 0.25f);
        v += bil(S3b, 32, y, x, 0.25f, 0.375f);
        feat[d] = v * (1.0f / 768.0f);
    }
    __syncthreads();
    float ao = 0.f, as = 0.f;
    for (int d = 0; d < 256; ++d) {
        float f = feat[d];
        ao = fmaf(f, ow1[d * 128 + t], ao);
        as = fmaf(f, sw1[d * 128 + t], as);
    }
    ho[t] = fmaxf(ao + ob1[t], 0.f);
    hs[t] = fmaxf(as + sb1[t], 0.f);
    __syncthreads();
    if (t < 3) {
        float acc = 0.f;
        if (t == 0)      { for (int j = 0; j < 128; ++j) acc = fmaf(ho[j], ow2[2 * j + 0], acc); acc += ob2[0]; }
        else if (t == 1) { for (int j = 0; j < 128; ++j) acc = fmaf(ho[j], ow2[2 * j + 1], acc); acc += ob2[1]; }
        else             { for (int j = 0; j < 128; ++j) acc = fmaf(hs[j], sw2[j],        acc); acc += sb2[0]; }
        res[t] = acc;
    }
    __syncthreads();
    if (t == 0) {
        int q = n & 63;  // q' of the output slot
        int cpx = (int)(qb[2 * q + 0] * 128.0f);
        int cpy = (int)(qb[2 * q + 1] * 128.0f);
        int cpsx = (int)((float)cpx + res[0] * 8.0f);  // trunc toward zero, matches astype(int32)
        int cpsy = (int)((float)cpy + res[1] * 8.0f);
        RS[n] = cpsx - 8;
        CS[n] = cpsy - 8;
        SC[n] = res[2];
    }
}

__global__ __launch_bounds__(256) void k_scalemap(
    const int* __restrict__ RS, const int* __restrict__ CS, const float* __restrict__ SC,
    float* __restrict__ SMAP) {
    __shared__ int rs[64], cs[64];
    __shared__ float sc[64];
    int t = threadIdx.x;
    int p = blockIdx.x * 256 + t;
    int b = p >> 14;
    if (t < 64) { rs[t] = RS[b * 64 + t]; cs[t] = CS[b * 64 + t]; sc[t] = SC[b * 64 + t]; }
    __syncthreads();
    int off = p & (HW1 - 1);
    int r = off >> 7, c = off & 127;
    float sv = 1.0f;
    for (int q = 63; q >= 0; --q) {
        int r0 = rs[q], c0 = cs[q];
        if (r0 >= 0 && c0 >= 0 && (unsigned)(r - r0) < 16u && (unsigned)(c - c0) < 16u) {
            sv = sc[q]; break;   // highest covering q == max tag
        }
    }
    SMAP[p] = sv;
}

// One block per (ch, b). ch<256: direct float4 FMA. 256..511: 2x bilinear from LDS.
// 512..767: 4x bilinear from LDS.
__global__ __launch_bounds__(256) void k_out(
    const float* __restrict__ a1, const float* __restrict__ a2, const float* __restrict__ a3,
    const float* __restrict__ n1, const float* __restrict__ n2, const float* __restrict__ n3,
    const float* __restrict__ SMAP, float* __restrict__ out) {
    __shared__ float cur[4096];
    __shared__ float nxt[4096];
    int ch = blockIdx.x;   // 0..767
    int b  = blockIdx.y;   // 0..3
    int t  = threadIdx.x;
    const float* smap = SMAP + b * HW1;
    float* o = out + ((size_t)(b * 768 + ch)) * HW1;
    if (ch < 256) {
        const float4* f  = (const float4*)(a1 + ((size_t)(b * 256 + ch)) * HW1);
        const float4* fn = (const float4*)(n1 + ((size_t)(b * 256 + ch)) * HW1);
        const float4* s4 = (const float4*)smap;
        float4* o4 = (float4*)o;
        for (int i = t; i < 4096; i += 256) {
            float4 fv = f[i], sv = s4[i], nv = fn[i];
            float4 r;
            r.x = fmaf(fv.x, sv.x, nv.x);
            r.y = fmaf(fv.y, sv.y, nv.y);
            r.z = fmaf(fv.z, sv.z, nv.z);
            r.w = fmaf(fv.w, sv.w, nv.w);
            o4[i] = r;
        }
    } else if (ch < 512) {
        int c2 = ch - 256;
        const float4* s0 = (const float4*)(a2 + ((size_t)(b * 256 + c2)) * HW2);
        const float4* s1 = (const float4*)(n2 + ((size_t)(b * 256 + c2)) * HW2);
        for (int i = t; i < 1024; i += 256) {
            ((float4*)cur)[i] = s0[i];
            ((float4*)nxt)[i] = s1[i];
        }
        __syncthreads();
        for (int p = t; p < HW1; p += 256) {
            int y = p >> 7, x = p & 127;
            float v  = bil(cur, 64, y, x, 0.5f, 0.25f);
            float vn = bil(nxt, 64, y, x, 0.5f, 0.25f);
            o[p] = fmaf(v, smap[p], vn);
        }
    } else {
        int c3 = ch - 512;
        const float4* s0 = (const float4*)(a3 + ((size_t)(b * 256 + c3)) * HW3);
        const float4* s1 = (const float4*)(n3 + ((size_t)(b * 256 + c3)) * HW3);
        for (int i = t; i < 256; i += 256) {
            ((float4*)cur)[i] = s0[i];
            ((float4*)nxt)[i] = s1[i];
        }
        __syncthreads();
        for (int p = t; p < HW1; p += 256) {
            int y = p >> 7, x = p & 127;
            float v  = bil(cur, 32, y, x, 0.25f, 0.375f);
            float vn = bil(nxt, 32, y, x, 0.25f, 0.375f);
            o[p] = fmaf(v, smap[p], vn);
        }
    }
}

extern "C" void kernel_launch(void* const* d_in, const int* in_sizes, int n_in,
                              void* d_out, int out_size, void* d_ws, size_t ws_size,
                              hipStream_t stream) {
    (void)in_sizes; (void)n_in; (void)out_size; (void)ws_size;
    const float* t0_l1 = (const float*)d_in[1];
    const float* t0_l2 = (const float*)d_in[2];
    const float* t0_l3 = (const float*)d_in[3];
    const float* t1_l1 = (const float*)d_in[5];
    const float* t1_l2 = (const float*)d_in[6];
    const float* t1_l3 = (const float*)d_in[7];
    const float* qb    = (const float*)d_in[8];
    const float* ow1   = (const float*)d_in[9];
    const float* ob1   = (const float*)d_in[10];
    const float* ow2   = (const float*)d_in[11];
    const float* ob2   = (const float*)d_in[12];
    const float* sw1   = (const float*)d_in[13];
    const float* sb1   = (const float*)d_in[14];
    const float* sw2   = (const float*)d_in[15];
    const float* sb2   = (const float*)d_in[16];

    char* ws = (char*)d_ws;
    float* SUM1 = (float*)(ws + 0);        // 262144 B : sum over 256 ch of t0_l1, (4,128,128)
    float* S2   = (float*)(ws + 262144);   //  65536 B : (4,64,64)
    float* S3   = (float*)(ws + 327680);   //  16384 B : (4,32,32)
    int*   RS   = (int*)  (ws + 344064);   //   1024 B : row start per (b',q')
    int*   CS   = (int*)  (ws + 345088);   //   1024 B : col start
    float* SC   = (float*)(ws + 346112);   //   1024 B : scale per (b',q')
    float* SMAP = (float*)(ws + 347136);   // 262144 B : (4,128,128) scale map
    float* out  = (float*)d_out;

    hipLaunchKernelGGL(k_sums, dim3(672), dim3(256), 0, stream,
                       t0_l1, t0_l2, t0_l3, SUM1, S2, S3);
    hipLaunchKernelGGL(k_query, dim3(256), dim3(128), 0, stream,
                       SUM1, S2, S3, qb, ow1, ob1, ow2, ob2, sw1, sb1, sw2, sb2, RS, CS, SC);
    hipLaunchKernelGGL(k_scalemap, dim3(256), dim3(256), 0, stream, RS, CS, SC, SMAP);
    hipLaunchKernelGGL(k_out, dim3(768, 4), dim3(256), 0, stream,
                       t0_l1, t0_l2, t0_l3, t1_l1, t1_l2, t1_l3, SMAP, out);
}

// Round 2
// 128.634 us; speedup vs baseline: 1.0246x; 1.0246x over previous
//
#include <hip/hip_runtime.h>

#define HW1 16384   // 128*128
#define HW2 4096    // 64*64
#define HW3 1024    // 32*32
#define NB  4
#define NCH 256

__device__ inline float4 f4add(float4 a, float4 b) {
    a.x += b.x; a.y += b.y; a.z += b.z; a.w += b.w; return a;
}

// clamp-to-edge half-pixel bilinear sample of an n x n map at output coord (y,x)
__device__ inline float bil(const float* m, int n, int y, int x, float scl, float off) {
    float fy = y * scl - off, fx = x * scl - off;
    float fy0 = floorf(fy), fx0 = floorf(fx);
    float wy = fy - fy0, wx = fx - fx0;
    int y0 = max((int)fy0, 0), y1 = min((int)fy0 + 1, n - 1);
    int x0 = max((int)fx0, 0), x1 = min((int)fx0 + 1, n - 1);
    float a = m[y0 * n + x0] * (1.f - wx) + m[y0 * n + x1] * wx;
    float b = m[y1 * n + x0] * (1.f - wx) + m[y1 * n + x1] * wx;
    return a * (1.f - wy) + b * wy;
}

// Channel sums of t0_l1 (128x128), t0_l2 (64x64), t0_l3 (32x32).
__global__ __launch_bounds__(256) void k_sums(
    const float* __restrict__ l1, const float* __restrict__ l2, const float* __restrict__ l3,
    float* __restrict__ SUM1, float* __restrict__ S2, float* __restrict__ S3) {
    __shared__ float4 red[256];
    int t = threadIdx.x, s = t >> 5, g = t & 31;
    int blk = blockIdx.x;
    const float* src; float* dst; int hw; int gg;
    if (blk < 512) {
        gg = blk * 32 + g; int p4 = gg * 4;
        int b = p4 >> 14, off = p4 & (HW1 - 1);
        src = l1 + ((size_t)(b * NCH + s * 32)) * HW1 + off; dst = SUM1; hw = HW1;
    } else if (blk < 640) {
        gg = (blk - 512) * 32 + g; int p4 = gg * 4;
        int b = p4 >> 12, off = p4 & (HW2 - 1);
        src = l2 + ((size_t)(b * NCH + s * 32)) * HW2 + off; dst = S2; hw = HW2;
    } else {
        gg = (blk - 640) * 32 + g; int p4 = gg * 4;
        int b = p4 >> 10, off = p4 & (HW3 - 1);
        src = l3 + ((size_t)(b * NCH + s * 32)) * HW3 + off; dst = S3; hw = HW3;
    }
    float4 acc = make_float4(0.f, 0.f, 0.f, 0.f);
    #pragma unroll 8
    for (int c = 0; c < 32; ++c)
        acc = f4add(acc, *(const float4*)(src + (size_t)c * hw));
    red[t] = acc;
    __syncthreads();
    if (s < 4) red[t] = f4add(red[t], red[t + 128]);
    __syncthreads();
    if (s < 2) red[t] = f4add(red[t], red[t + 64]);
    __syncthreads();
    if (s == 0) {
        float4 r = f4add(red[t], red[t + 32]);
        ((float4*)dst)[gg] = r;
    }
}

// One block per output row n = b'*64 + q'.
__global__ __launch_bounds__(128) void k_query(
    const float* __restrict__ SUM1, const float* __restrict__ S2, const float* __restrict__ S3,
    const float* __restrict__ qb,
    const float* __restrict__ ow1, const float* __restrict__ ob1,
    const float* __restrict__ ow2, const float* __restrict__ ob2,
    const float* __restrict__ sw1, const float* __restrict__ sb1,
    const float* __restrict__ sw2, const float* __restrict__ sb2,
    int* __restrict__ RS, int* __restrict__ CS, float* __restrict__ SC) {
    __shared__ float feat[256];
    __shared__ float ho[128], hs[128];
    __shared__ float res[3];
    int n = blockIdx.x, t = threadIdx.x;
    int b = n & 3, qp = n >> 2;
    int qi = qp >> 3, qj = qp & 7;
    const float* S2b = S2 + b * HW2;
    const float* S3b = S3 + b * HW3;
    for (int d = t; d < 256; d += 128) {
        int i = d >> 4, j = d & 15;
        int y = 16 * qi + i, x = 16 * qj + j;
        float v = SUM1[b * HW1 + y * 128 + x];
        v += bil(S2b, 64, y, x, 0.5f, 0.25f);
        v += bil(S3b, 32, y, x, 0.25f, 0.375f);
        feat[d] = v * (1.0f / 768.0f);
    }
    __syncthreads();
    float ao = 0.f, as = 0.f;
    for (int d = 0; d < 256; ++d) {
        float f = feat[d];
        ao = fmaf(f, ow1[d * 128 + t], ao);
        as = fmaf(f, sw1[d * 128 + t], as);
    }
    ho[t] = fmaxf(ao + ob1[t], 0.f);
    hs[t] = fmaxf(as + sb1[t], 0.f);
    __syncthreads();
    if (t < 3) {
        float acc = 0.f;
        if (t == 0)      { for (int j = 0; j < 128; ++j) acc = fmaf(ho[j], ow2[2 * j + 0], acc); acc += ob2[0]; }
        else if (t == 1) { for (int j = 0; j < 128; ++j) acc = fmaf(ho[j], ow2[2 * j + 1], acc); acc += ob2[1]; }
        else             { for (int j = 0; j < 128; ++j) acc = fmaf(hs[j], sw2[j],        acc); acc += sb2[0]; }
        res[t] = acc;
    }
    __syncthreads();
    if (t == 0) {
        int q = n & 63;
        int cpx = (int)(qb[2 * q + 0] * 128.0f);
        int cpy = (int)(qb[2 * q + 1] * 128.0f);
        int cpsx = (int)((float)cpx + res[0] * 8.0f);
        int cpsy = (int)((float)cpy + res[1] * 8.0f);
        RS[n] = cpsx - 8;
        CS[n] = cpsy - 8;
        SC[n] = res[2];
    }
}

__global__ __launch_bounds__(256) void k_scalemap(
    const int* __restrict__ RS, const int* __restrict__ CS, const float* __restrict__ SC,
    float* __restrict__ SMAP) {
    __shared__ int rs[64], cs[64];
    __shared__ float sc[64];
    int t = threadIdx.x;
    int p = blockIdx.x * 256 + t;
    int b = p >> 14;
    if (t < 64) { rs[t] = RS[b * 64 + t]; cs[t] = CS[b * 64 + t]; sc[t] = SC[b * 64 + t]; }
    __syncthreads();
    int off = p & (HW1 - 1);
    int r = off >> 7, c = off & 127;
    float sv = 1.0f;
    for (int q = 63; q >= 0; --q) {
        int r0 = rs[q], c0 = cs[q];
        if (r0 >= 0 && c0 >= 0 && (unsigned)(r - r0) < 16u && (unsigned)(c - c0) < 16u) {
            sv = sc[q]; break;
        }
    }
    SMAP[p] = sv;
}

// One block per (ch, b). ch<256: direct float4 FMA.
// 256..511: 2x bilinear, 4 outputs/iter via parity weights.
// 512..767: 4x bilinear, 4 outputs/iter.
__global__ __launch_bounds__(256) void k_out(
    const float* __restrict__ a1, const float* __restrict__ a2, const float* __restrict__ a3,
    const float* __restrict__ n1, const float* __restrict__ n2, const float* __restrict__ n3,
    const float* __restrict__ SMAP, float* __restrict__ out) {
    __shared__ float cur[4096];
    __shared__ float nxt[4096];
    int ch = blockIdx.x;
    int b  = blockIdx.y;
    int t  = threadIdx.x;
    const float* smap = SMAP + b * HW1;
    const float4* s4 = (const float4*)smap;
    float* o = out + ((size_t)(b * 768 + ch)) * HW1;
    float4* o4 = (float4*)o;
    if (ch < 256) {
        const float4* f  = (const float4*)(a1 + ((size_t)(b * 256 + ch)) * HW1);
        const float4* fn = (const float4*)(n1 + ((size_t)(b * 256 + ch)) * HW1);
        for (int i = t; i < 4096; i += 256) {
            float4 fv = f[i], sv = s4[i], nv = fn[i];
            float4 r;
            r.x = fmaf(fv.x, sv.x, nv.x);
            r.y = fmaf(fv.y, sv.y, nv.y);
            r.z = fmaf(fv.z, sv.z, nv.z);
            r.w = fmaf(fv.w, sv.w, nv.w);
            o4[i] = r;
        }
    } else if (ch < 512) {
        int c2 = ch - 256;
        const float4* s0 = (const float4*)(a2 + ((size_t)(b * 256 + c2)) * HW2);
        const float4* s1 = (const float4*)(n2 + ((size_t)(b * 256 + c2)) * HW2);
        for (int i = t; i < 1024; i += 256) {
            ((float4*)cur)[i] = s0[i];
            ((float4*)nxt)[i] = s1[i];
        }
        __syncthreads();
        // output group: 4 consecutive x per iter. y0=(y-1)>>1 clamped; wy on y1 row.
        for (int i = t; i < 4096; i += 256) {
            int y = i >> 5, j = i & 31;
            int iy = (y - 1) >> 1;
            int y0 = max(iy, 0), y1 = min(iy + 1, 63);
            float wy = (y & 1) ? 0.25f : 0.75f;
            int cm1 = max(2 * j - 1, 0);
            int c0 = 2 * j, c1 = 2 * j + 1;
            int c2c = min(2 * j + 2, 63);
            const float* r0 = cur + y0 * 64; const float* r1 = cur + y1 * 64;
            const float* u0 = nxt + y0 * 64; const float* u1 = nxt + y1 * 64;
            float a0 = r0[cm1], a1v = r0[c0], a2v = r0[c1], a3v = r0[c2c];
            float b0 = r1[cm1], b1v = r1[c0], b2v = r1[c1], b3v = r1[c2c];
            float p0 = u0[cm1], p1 = u0[c0], p2 = u0[c1], p3 = u0[c2c];
            float q0 = u1[cm1], q1 = u1[c0], q2 = u1[c1], q3 = u1[c2c];
            // horizontal: even x -> .25*left+.75*right ; odd x -> .75*left+.25*right
            float h0 = fmaf(0.25f, a0, 0.75f * a1v);
            float h1 = fmaf(0.75f, a1v, 0.25f * a2v);
            float h2 = fmaf(0.25f, a1v, 0.75f * a2v);
            float h3 = fmaf(0.75f, a2v, 0.25f * a3v);
            float g0 = fmaf(0.25f, b0, 0.75f * b1v);
            float g1 = fmaf(0.75f, b1v, 0.25f * b2v);
            float g2 = fmaf(0.25f, b1v, 0.75f * b2v);
            float g3 = fmaf(0.75f, b2v, 0.25f * b3v);
            float e0 = fmaf(0.25f, p0, 0.75f * p1);
            float e1 = fmaf(0.75f, p1, 0.25f * p2);
            float e2 = fmaf(0.25f, p1, 0.75f * p2);
            float e3 = fmaf(0.75f, p2, 0.25f * p3);
            float k0 = fmaf(0.25f, q0, 0.75f * q1);
            float k1 = fmaf(0.75f, q1, 0.25f * q2);
            float k2 = fmaf(0.25f, q1, 0.75f * q2);
            float k3 = fmaf(0.75f, q2, 0.25f * q3);
            float4 sv = s4[i];
            float4 r;
            r.x = fmaf(fmaf(g0 - h0, wy, h0), sv.x, fmaf(k0 - e0, wy, e0));
            r.y = fmaf(fmaf(g1 - h1, wy, h1), sv.y, fmaf(k1 - e1, wy, e1));
            r.z = fmaf(fmaf(g2 - h2, wy, h2), sv.z, fmaf(k2 - e2, wy, e2));
            r.w = fmaf(fmaf(g3 - h3, wy, h3), sv.w, fmaf(k3 - e3, wy, e3));
            o4[i] = r;
        }
    } else {
        int c3 = ch - 512;
        const float4* s0 = (const float4*)(a3 + ((size_t)(b * 256 + c3)) * HW3);
        const float4* s1 = (const float4*)(n3 + ((size_t)(b * 256 + c3)) * HW3);
        for (int i = t; i < 256; i += 256) {
            ((float4*)cur)[i] = s0[i];
            ((float4*)nxt)[i] = s1[i];
        }
        __syncthreads();
        // 4x: y0=(y-2)>>2 clamped; wx pattern by x&3: .625,.875,.125,.375
        for (int i = t; i < 4096; i += 256) {
            int y = i >> 5, j = i & 31;
            int iy = (y - 2) >> 2;
            int y0 = max(iy, 0), y1 = min(iy + 1, 31);
            int ym = y & 3;
            float wy = (ym < 2) ? (0.625f + 0.25f * ym) : (0.25f * ym - 0.375f);
            int cm1 = max(j - 1, 0);
            int c0 = j, c1 = min(j + 1, 31);
            const float* r0 = cur + y0 * 32; const float* r1 = cur + y1 * 32;
            const float* u0 = nxt + y0 * 32; const float* u1 = nxt + y1 * 32;
            float a0 = r0[cm1], a1v = r0[c0], a2v = r0[c1];
            float b0 = r1[cm1], b1v = r1[c0], b2v = r1[c1];
            float p0 = u0[cm1], p1 = u0[c0], p2 = u0[c1];
            float q0 = u1[cm1], q1 = u1[c0], q2 = u1[c1];
            float h0 = fmaf(0.375f, a0, 0.625f * a1v);
            float h1 = fmaf(0.125f, a0, 0.875f * a1v);
            float h2 = fmaf(0.875f, a1v, 0.125f * a2v);
            float h3 = fmaf(0.625f, a1v, 0.375f * a2v);
            float g0 = fmaf(0.375f, b0, 0.625f * b1v);
            float g1 = fmaf(0.125f, b0, 0.875f * b1v);
            float g2 = fmaf(0.875f, b1v, 0.125f * b2v);
            float g3 = fmaf(0.625f, b1v, 0.375f * b2v);
            float e0 = fmaf(0.375f, p0, 0.625f * p1);
            float e1 = fmaf(0.125f, p0, 0.875f * p1);
            float e2 = fmaf(0.875f, p1, 0.125f * p2);
            float e3 = fmaf(0.625f, p1, 0.375f * p2);
            float k0 = fmaf(0.375f, q0, 0.625f * q1);
            float k1 = fmaf(0.125f, q0, 0.875f * q1);
            float k2 = fmaf(0.875f, q1, 0.125f * q2);
            float k3 = fmaf(0.625f, q1, 0.375f * q2);
            float4 sv = s4[i];
            float4 r;
            r.x = fmaf(fmaf(g0 - h0, wy, h0), sv.x, fmaf(k0 - e0, wy, e0));
            r.y = fmaf(fmaf(g1 - h1, wy, h1), sv.y, fmaf(k1 - e1, wy, e1));
            r.z = fmaf(fmaf(g2 - h2, wy, h2), sv.z, fmaf(k2 - e2, wy, e2));
            r.w = fmaf(fmaf(g3 - h3, wy, h3), sv.w, fmaf(k3 - e3, wy, e3));
            o4[i] = r;
        }
    }
}

extern "C" void kernel_launch(void* const* d_in, const int* in_sizes, int n_in,
                              void* d_out, int out_size, void* d_ws, size_t ws_size,
                              hipStream_t stream) {
    (void)in_sizes; (void)n_in; (void)out_size; (void)ws_size;
    const float* t0_l1 = (const float*)d_in[1];
    const float* t0_l2 = (const float*)d_in[2];
    const float* t0_l3 = (const float*)d_in[3];
    const float* t1_l1 = (const float*)d_in[5];
    const float* t1_l2 = (const float*)d_in[6];
    const float* t1_l3 = (const float*)d_in[7];
    const float* qb    = (const float*)d_in[8];
    const float* ow1   = (const float*)d_in[9];
    const float* ob1   = (const float*)d_in[10];
    const float* ow2   = (const float*)d_in[11];
    const float* ob2   = (const float*)d_in[12];
    const float* sw1   = (const float*)d_in[13];
    const float* sb1   = (const float*)d_in[14];
    const float* sw2   = (const float*)d_in[15];
    const float* sb2   = (const float*)d_in[16];

    char* ws = (char*)d_ws;
    float* SUM1 = (float*)(ws + 0);
    float* S2   = (float*)(ws + 262144);
    float* S3   = (float*)(ws + 327680);
    int*   RS   = (int*)  (ws + 344064);
    int*   CS   = (int*)  (ws + 345088);
    float* SC   = (float*)(ws + 346112);
    float* SMAP = (float*)(ws + 347136);
    float* out  = (float*)d_out;

    hipLaunchKernelGGL(k_sums, dim3(672), dim3(256), 0, stream,
                       t0_l1, t0_l2, t0_l3, SUM1, S2, S3);
    hipLaunchKernelGGL(k_query, dim3(256), dim3(128), 0, stream,
                       SUM1, S2, S3, qb, ow1, ob1, ow2, ob2, sw1, sb1, sw2, sb2, RS, CS, SC);
    hipLaunchKernelGGL(k_scalemap, dim3(256), dim3(256), 0, stream, RS, CS, SC, SMAP);
    hipLaunchKernelGGL(k_out, dim3(768, 4), dim3(256), 0, stream,
                       t0_l1, t0_l2, t0_l3, t1_l1, t1_l2, t1_l3, SMAP, out);
}

// Round 3
// 109.789 us; speedup vs baseline: 1.2005x; 1.1716x over previous
//
#include <hip/hip_runtime.h>

#define HW1 16384   // 128*128
#define HW2 4096    // 64*64
#define HW3 1024    // 32*32
#define NB  4
#define NCH 256

typedef float f4 __attribute__((ext_vector_type(4)));

__device__ inline float4 f4add(float4 a, float4 b) {
    a.x += b.x; a.y += b.y; a.z += b.z; a.w += b.w; return a;
}

// clamp-to-edge half-pixel bilinear sample of an n x n map at output coord (y,x)
__device__ inline float bil(const float* m, int n, int y, int x, float scl, float off) {
    float fy = y * scl - off, fx = x * scl - off;
    float fy0 = floorf(fy), fx0 = floorf(fx);
    float wy = fy - fy0, wx = fx - fx0;
    int y0 = max((int)fy0, 0), y1 = min((int)fy0 + 1, n - 1);
    int x0 = max((int)fx0, 0), x1 = min((int)fx0 + 1, n - 1);
    float a = m[y0 * n + x0] * (1.f - wx) + m[y0 * n + x1] * wx;
    float b = m[y1 * n + x0] * (1.f - wx) + m[y1 * n + x1] * wx;
    return a * (1.f - wy) + b * wy;
}

// Channel sums of t0_l1 (128x128), t0_l2 (64x64), t0_l3 (32x32).
__global__ __launch_bounds__(256) void k_sums(
    const float* __restrict__ l1, const float* __restrict__ l2, const float* __restrict__ l3,
    float* __restrict__ SUM1, float* __restrict__ S2, float* __restrict__ S3) {
    __shared__ float4 red[256];
    int t = threadIdx.x, s = t >> 5, g = t & 31;
    int blk = blockIdx.x;
    const float* src; float* dst; int hw; int gg;
    if (blk < 512) {
        gg = blk * 32 + g; int p4 = gg * 4;
        int b = p4 >> 14, off = p4 & (HW1 - 1);
        src = l1 + ((size_t)(b * NCH + s * 32)) * HW1 + off; dst = SUM1; hw = HW1;
    } else if (blk < 640) {
        gg = (blk - 512) * 32 + g; int p4 = gg * 4;
        int b = p4 >> 12, off = p4 & (HW2 - 1);
        src = l2 + ((size_t)(b * NCH + s * 32)) * HW2 + off; dst = S2; hw = HW2;
    } else {
        gg = (blk - 640) * 32 + g; int p4 = gg * 4;
        int b = p4 >> 10, off = p4 & (HW3 - 1);
        src = l3 + ((size_t)(b * NCH + s * 32)) * HW3 + off; dst = S3; hw = HW3;
    }
    float4 acc = make_float4(0.f, 0.f, 0.f, 0.f);
    #pragma unroll 8
    for (int c = 0; c < 32; ++c)
        acc = f4add(acc, *(const float4*)(src + (size_t)c * hw));
    red[t] = acc;
    __syncthreads();
    if (s < 4) red[t] = f4add(red[t], red[t + 128]);
    __syncthreads();
    if (s < 2) red[t] = f4add(red[t], red[t + 64]);
    __syncthreads();
    if (s == 0) {
        float4 r = f4add(red[t], red[t + 32]);
        ((float4*)dst)[gg] = r;
    }
}

// One block (256 thr) per output row n = b'*64 + q'.
__global__ __launch_bounds__(256) void k_query(
    const float* __restrict__ SUM1, const float* __restrict__ S2, const float* __restrict__ S3,
    const float* __restrict__ qb,
    const float* __restrict__ ow1, const float* __restrict__ ob1,
    const float* __restrict__ ow2, const float* __restrict__ ob2,
    const float* __restrict__ sw1, const float* __restrict__ sb1,
    const float* __restrict__ sw2, const float* __restrict__ sb2,
    int* __restrict__ RS, int* __restrict__ CS, float* __restrict__ SC) {
    __shared__ float feat[256];
    __shared__ float hid[256];     // [0:128)=ho, [128:256)=hs
    __shared__ float res[3];
    int n = blockIdx.x, t = threadIdx.x;
    int b = n & 3, qp = n >> 2;
    int qi = qp >> 3, qj = qp & 7;
    {
        int i = t >> 4, j = t & 15;
        int y = 16 * qi + i, x = 16 * qj + j;
        float v = SUM1[b * HW1 + y * 128 + x];
        v += bil(S2 + b * HW2, 64, y, x, 0.5f, 0.25f);
        v += bil(S3 + b * HW3, 32, y, x, 0.25f, 0.375f);
        feat[t] = v * (1.0f / 768.0f);
    }
    __syncthreads();
    {
        int h = t & 127;
        const float* W  = (t < 128) ? ow1 : sw1;
        const float* Bv = (t < 128) ? ob1 : sb1;
        float acc = 0.f;
        #pragma unroll 8
        for (int d = 0; d < 256; ++d)
            acc = fmaf(feat[d], W[d * 128 + h], acc);
        hid[t] = fmaxf(acc + Bv[h], 0.f);
    }
    __syncthreads();
    int w = t >> 6, l = t & 63;
    if (w < 3) {
        float acc;
        if (w == 0)      acc = fmaf(hid[l], ow2[2 * l],     hid[l + 64] * ow2[2 * l + 128]);
        else if (w == 1) acc = fmaf(hid[l], ow2[2 * l + 1], hid[l + 64] * ow2[2 * l + 129]);
        else             acc = fmaf(hid[128 + l], sw2[l],   hid[192 + l] * sw2[l + 64]);
        #pragma unroll
        for (int off = 32; off; off >>= 1) acc += __shfl_down(acc, off);
        if (l == 0) res[w] = acc + (w == 0 ? ob2[0] : (w == 1 ? ob2[1] : sb2[0]));
    }
    __syncthreads();
    if (t == 0) {
        int q = n & 63;
        int cpx = (int)(qb[2 * q + 0] * 128.0f);
        int cpy = (int)(qb[2 * q + 1] * 128.0f);
        int cpsx = (int)((float)cpx + res[0] * 8.0f);
        int cpsy = (int)((float)cpy + res[1] * 8.0f);
        RS[n] = cpsx - 8;
        CS[n] = cpsy - 8;
        SC[n] = res[2];
    }
}

__global__ __launch_bounds__(256) void k_scalemap(
    const int* __restrict__ RS, const int* __restrict__ CS, const float* __restrict__ SC,
    float* __restrict__ SMAP) {
    __shared__ int rs[64], cs[64];
    __shared__ float sc[64];
    int t = threadIdx.x;
    int p = blockIdx.x * 256 + t;
    int b = p >> 14;
    if (t < 64) { rs[t] = RS[b * 64 + t]; cs[t] = CS[b * 64 + t]; sc[t] = SC[b * 64 + t]; }
    __syncthreads();
    int off = p & (HW1 - 1);
    int r = off >> 7, c = off & 127;
    float sv = 1.0f;
    for (int q = 63; q >= 0; --q) {
        int r0 = rs[q], c0 = cs[q];
        if (r0 >= 0 && c0 >= 0 && (unsigned)(r - r0) < 16u && (unsigned)(c - c0) < 16u) {
            sv = sc[q]; break;
        }
    }
    SMAP[p] = sv;
}

// One block per (ch, b). t1 streams use non-temporal loads; out uses NT stores
// so the 201 MB write stream doesn't evict t0 data from L2/L3.
__global__ __launch_bounds__(256) void k_out(
    const float* __restrict__ a1, const float* __restrict__ a2, const float* __restrict__ a3,
    const float* __restrict__ n1, const float* __restrict__ n2, const float* __restrict__ n3,
    const float* __restrict__ SMAP, float* __restrict__ out) {
    __shared__ float cur[4096];
    __shared__ float nxt[4096];
    int ch = blockIdx.x;
    int b  = blockIdx.y;
    int t  = threadIdx.x;
    const f4* s4 = (const f4*)(SMAP + b * HW1);
    f4* o4 = (f4*)(out + ((size_t)(b * 768 + ch)) * HW1);
    if (ch < 256) {
        const f4* f  = (const f4*)(a1 + ((size_t)(b * 256 + ch)) * HW1);
        const f4* fn = (const f4*)(n1 + ((size_t)(b * 256 + ch)) * HW1);
        for (int i = t; i < 4096; i += 256) {
            f4 fv = f[i];
            f4 sv = s4[i];
            f4 nv = __builtin_nontemporal_load(&fn[i]);
            f4 r;
            r.x = fmaf(fv.x, sv.x, nv.x);
            r.y = fmaf(fv.y, sv.y, nv.y);
            r.z = fmaf(fv.z, sv.z, nv.z);
            r.w = fmaf(fv.w, sv.w, nv.w);
            __builtin_nontemporal_store(r, &o4[i]);
        }
    } else if (ch < 512) {
        int c2 = ch - 256;
        const f4* s0 = (const f4*)(a2 + ((size_t)(b * 256 + c2)) * HW2);
        const f4* s1 = (const f4*)(n2 + ((size_t)(b * 256 + c2)) * HW2);
        for (int i = t; i < 1024; i += 256) {
            ((f4*)cur)[i] = s0[i];
            ((f4*)nxt)[i] = __builtin_nontemporal_load(&s1[i]);
        }
        __syncthreads();
        for (int i = t; i < 4096; i += 256) {
            int y = i >> 5, j = i & 31;
            int iy = (y - 1) >> 1;
            int y0 = max(iy, 0), y1 = min(iy + 1, 63);
            float wy = (y & 1) ? 0.25f : 0.75f;
            int cm1 = max(2 * j - 1, 0);
            int c0 = 2 * j, c1 = 2 * j + 1;
            int c2c = min(2 * j + 2, 63);
            const float* r0 = cur + y0 * 64; const float* r1 = cur + y1 * 64;
            const float* u0 = nxt + y0 * 64; const float* u1 = nxt + y1 * 64;
            float a0 = r0[cm1], a1v = r0[c0], a2v = r0[c1], a3v = r0[c2c];
            float b0 = r1[cm1], b1v = r1[c0], b2v = r1[c1], b3v = r1[c2c];
            float p0 = u0[cm1], p1 = u0[c0], p2 = u0[c1], p3 = u0[c2c];
            float q0 = u1[cm1], q1 = u1[c0], q2 = u1[c1], q3 = u1[c2c];
            float h0 = fmaf(0.25f, a0, 0.75f * a1v);
            float h1 = fmaf(0.75f, a1v, 0.25f * a2v);
            float h2 = fmaf(0.25f, a1v, 0.75f * a2v);
            float h3 = fmaf(0.75f, a2v, 0.25f * a3v);
            float g0 = fmaf(0.25f, b0, 0.75f * b1v);
            float g1 = fmaf(0.75f, b1v, 0.25f * b2v);
            float g2 = fmaf(0.25f, b1v, 0.75f * b2v);
            float g3 = fmaf(0.75f, b2v, 0.25f * b3v);
            float e0 = fmaf(0.25f, p0, 0.75f * p1);
            float e1 = fmaf(0.75f, p1, 0.25f * p2);
            float e2 = fmaf(0.25f, p1, 0.75f * p2);
            float e3 = fmaf(0.75f, p2, 0.25f * p3);
            float k0 = fmaf(0.25f, q0, 0.75f * q1);
            float k1 = fmaf(0.75f, q1, 0.25f * q2);
            float k2 = fmaf(0.25f, q1, 0.75f * q2);
            float k3 = fmaf(0.75f, q2, 0.25f * q3);
            f4 sv = s4[i];
            f4 r;
            r.x = fmaf(fmaf(g0 - h0, wy, h0), sv.x, fmaf(k0 - e0, wy, e0));
            r.y = fmaf(fmaf(g1 - h1, wy, h1), sv.y, fmaf(k1 - e1, wy, e1));
            r.z = fmaf(fmaf(g2 - h2, wy, h2), sv.z, fmaf(k2 - e2, wy, e2));
            r.w = fmaf(fmaf(g3 - h3, wy, h3), sv.w, fmaf(k3 - e3, wy, e3));
            __builtin_nontemporal_store(r, &o4[i]);
        }
    } else {
        int c3 = ch - 512;
        const f4* s0 = (const f4*)(a3 + ((size_t)(b * 256 + c3)) * HW3);
        const f4* s1 = (const f4*)(n3 + ((size_t)(b * 256 + c3)) * HW3);
        if (t < 256) {
            for (int i = t; i < 256; i += 256) {
                ((f4*)cur)[i] = s0[i];
                ((f4*)nxt)[i] = __builtin_nontemporal_load(&s1[i]);
            }
        }
        __syncthreads();
        for (int i = t; i < 4096; i += 256) {
            int y = i >> 5, j = i & 31;
            int iy = (y - 2) >> 2;
            int y0 = max(iy, 0), y1 = min(iy + 1, 31);
            int ym = y & 3;
            float wy = (ym < 2) ? (0.625f + 0.25f * ym) : (0.25f * ym - 0.375f);
            int cm1 = max(j - 1, 0);
            int c0 = j, c1 = min(j + 1, 31);
            const float* r0 = cur + y0 * 32; const float* r1 = cur + y1 * 32;
            const float* u0 = nxt + y0 * 32; const float* u1 = nxt + y1 * 32;
            float a0 = r0[cm1], a1v = r0[c0], a2v = r0[c1];
            float b0 = r1[cm1], b1v = r1[c0], b2v = r1[c1];
            float p0 = u0[cm1], p1 = u0[c0], p2 = u0[c1];
            float q0 = u1[cm1], q1 = u1[c0], q2 = u1[c1];
            float h0 = fmaf(0.375f, a0, 0.625f * a1v);
            float h1 = fmaf(0.125f, a0, 0.875f * a1v);
            float h2 = fmaf(0.875f, a1v, 0.125f * a2v);
            float h3 = fmaf(0.625f, a1v, 0.375f * a2v);
            float g0 = fmaf(0.375f, b0, 0.625f * b1v);
            float g1 = fmaf(0.125f, b0, 0.875f * b1v);
            float g2 = fmaf(0.875f, b1v, 0.125f * b2v);
            float g3 = fmaf(0.625f, b1v, 0.375f * b2v);
            float e0 = fmaf(0.375f, p0, 0.625f * p1);
            float e1 = fmaf(0.125f, p0, 0.875f * p1);
            float e2 = fmaf(0.875f, p1, 0.125f * p2);
            float e3 = fmaf(0.625f, p1, 0.375f * p2);
            float k0 = fmaf(0.375f, q0, 0.625f * q1);
            float k1 = fmaf(0.125f, q0, 0.875f * q1);
            float k2 = fmaf(0.875f, q1, 0.125f * q2);
            float k3 = fmaf(0.625f, q1, 0.375f * q2);
            f4 sv = s4[i];
            f4 r;
            r.x = fmaf(fmaf(g0 - h0, wy, h0), sv.x, fmaf(k0 - e0, wy, e0));
            r.y = fmaf(fmaf(g1 - h1, wy, h1), sv.y, fmaf(k1 - e1, wy, e1));
            r.z = fmaf(fmaf(g2 - h2, wy, h2), sv.z, fmaf(k2 - e2, wy, e2));
            r.w = fmaf(fmaf(g3 - h3, wy, h3), sv.w, fmaf(k3 - e3, wy, e3));
            __builtin_nontemporal_store(r, &o4[i]);
        }
    }
}

extern "C" void kernel_launch(void* const* d_in, const int* in_sizes, int n_in,
                              void* d_out, int out_size, void* d_ws, size_t ws_size,
                              hipStream_t stream) {
    (void)in_sizes; (void)n_in; (void)out_size; (void)ws_size;
    const float* t0_l1 = (const float*)d_in[1];
    const float* t0_l2 = (const float*)d_in[2];
    const float* t0_l3 = (const float*)d_in[3];
    const float* t1_l1 = (const float*)d_in[5];
    const float* t1_l2 = (const float*)d_in[6];
    const float* t1_l3 = (const float*)d_in[7];
    const float* qb    = (const float*)d_in[8];
    const float* ow1   = (const float*)d_in[9];
    const float* ob1   = (const float*)d_in[10];
    const float* ow2   = (const float*)d_in[11];
    const float* ob2   = (const float*)d_in[12];
    const float* sw1   = (const float*)d_in[13];
    const float* sb1   = (const float*)d_in[14];
    const float* sw2   = (const float*)d_in[15];
    const float* sb2   = (const float*)d_in[16];

    char* ws = (char*)d_ws;
    float* SUM1 = (float*)(ws + 0);
    float* S2   = (float*)(ws + 262144);
    float* S3   = (float*)(ws + 327680);
    int*   RS   = (int*)  (ws + 344064);
    int*   CS   = (int*)  (ws + 345088);
    float* SC   = (float*)(ws + 346112);
    float* SMAP = (float*)(ws + 347136);
    float* out  = (float*)d_out;

    hipLaunchKernelGGL(k_sums, dim3(672), dim3(256), 0, stream,
                       t0_l1, t0_l2, t0_l3, SUM1, S2, S3);
    hipLaunchKernelGGL(k_query, dim3(256), dim3(256), 0, stream,
                       SUM1, S2, S3, qb, ow1, ob1, ow2, ob2, sw1, sb1, sw2, sb2, RS, CS, SC);
    hipLaunchKernelGGL(k_scalemap, dim3(256), dim3(256), 0, stream, RS, CS, SC, SMAP);
    hipLaunchKernelGGL(k_out, dim3(768, 4), dim3(256), 0, stream,
                       t0_l1, t0_l2, t0_l3, t1_l1, t1_l2, t1_l3, SMAP, out);
}

// Round 4
// 103.261 us; speedup vs baseline: 1.2764x; 1.0632x over previous
//
#include <hip/hip_runtime.h>

#define HW1 16384   // 128*128
#define HW2 4096    // 64*64
#define HW3 1024    // 32*32
#define NB  4
#define NCH 256

typedef float f4 __attribute__((ext_vector_type(4)));

__device__ inline float4 f4add(float4 a, float4 b) {
    a.x += b.x; a.y += b.y; a.z += b.z; a.w += b.w; return a;
}

// clamp-to-edge half-pixel bilinear sample of an n x n map at output coord (y,x)
__device__ inline float bil(const float* m, int n, int y, int x, float scl, float off) {
    float fy = y * scl - off, fx = x * scl - off;
    float fy0 = floorf(fy), fx0 = floorf(fx);
    float wy = fy - fy0, wx = fx - fx0;
    int y0 = max((int)fy0, 0), y1 = min((int)fy0 + 1, n - 1);
    int x0 = max((int)fx0, 0), x1 = min((int)fx0 + 1, n - 1);
    float a = m[y0 * n + x0] * (1.f - wx) + m[y0 * n + x1] * wx;
    float b = m[y1 * n + x0] * (1.f - wx) + m[y1 * n + x1] * wx;
    return a * (1.f - wy) + b * wy;
}

// Channel sums of t0_l1 (128x128), t0_l2 (64x64), t0_l3 (32x32).
__global__ __launch_bounds__(256) void k_sums(
    const float* __restrict__ l1, const float* __restrict__ l2, const float* __restrict__ l3,
    float* __restrict__ SUM1, float* __restrict__ S2, float* __restrict__ S3) {
    __shared__ float4 red[256];
    int t = threadIdx.x, s = t >> 5, g = t & 31;
    int blk = blockIdx.x;
    const float* src; float* dst; int hw; int gg;
    if (blk < 512) {
        gg = blk * 32 + g; int p4 = gg * 4;
        int b = p4 >> 14, off = p4 & (HW1 - 1);
        src = l1 + ((size_t)(b * NCH + s * 32)) * HW1 + off; dst = SUM1; hw = HW1;
    } else if (blk < 640) {
        gg = (blk - 512) * 32 + g; int p4 = gg * 4;
        int b = p4 >> 12, off = p4 & (HW2 - 1);
        src = l2 + ((size_t)(b * NCH + s * 32)) * HW2 + off; dst = S2; hw = HW2;
    } else {
        gg = (blk - 640) * 32 + g; int p4 = gg * 4;
        int b = p4 >> 10, off = p4 & (HW3 - 1);
        src = l3 + ((size_t)(b * NCH + s * 32)) * HW3 + off; dst = S3; hw = HW3;
    }
    float4 acc = make_float4(0.f, 0.f, 0.f, 0.f);
    #pragma unroll 8
    for (int c = 0; c < 32; ++c)
        acc = f4add(acc, *(const float4*)(src + (size_t)c * hw));
    red[t] = acc;
    __syncthreads();
    if (s < 4) red[t] = f4add(red[t], red[t + 128]);
    __syncthreads();
    if (s < 2) red[t] = f4add(red[t], red[t + 64]);
    __syncthreads();
    if (s == 0) {
        float4 r = f4add(red[t], red[t + 32]);
        ((float4*)dst)[gg] = r;
    }
}

// One block (256 thr) per output row n = b'*64 + q'.
__global__ __launch_bounds__(256) void k_query(
    const float* __restrict__ SUM1, const float* __restrict__ S2, const float* __restrict__ S3,
    const float* __restrict__ qb,
    const float* __restrict__ ow1, const float* __restrict__ ob1,
    const float* __restrict__ ow2, const float* __restrict__ ob2,
    const float* __restrict__ sw1, const float* __restrict__ sb1,
    const float* __restrict__ sw2, const float* __restrict__ sb2,
    int* __restrict__ RS, int* __restrict__ CS, float* __restrict__ SC) {
    __shared__ float feat[256];
    __shared__ float hid[256];
    __shared__ float res[3];
    int n = blockIdx.x, t = threadIdx.x;
    int b = n & 3, qp = n >> 2;
    int qi = qp >> 3, qj = qp & 7;
    {
        int i = t >> 4, j = t & 15;
        int y = 16 * qi + i, x = 16 * qj + j;
        float v = SUM1[b * HW1 + y * 128 + x];
        v += bil(S2 + b * HW2, 64, y, x, 0.5f, 0.25f);
        v += bil(S3 + b * HW3, 32, y, x, 0.25f, 0.375f);
        feat[t] = v * (1.0f / 768.0f);
    }
    __syncthreads();
    {
        int h = t & 127;
        const float* W  = (t < 128) ? ow1 : sw1;
        const float* Bv = (t < 128) ? ob1 : sb1;
        float acc = 0.f;
        #pragma unroll 8
        for (int d = 0; d < 256; ++d)
            acc = fmaf(feat[d], W[d * 128 + h], acc);
        hid[t] = fmaxf(acc + Bv[h], 0.f);
    }
    __syncthreads();
    int w = t >> 6, l = t & 63;
    if (w < 3) {
        float acc;
        if (w == 0)      acc = fmaf(hid[l], ow2[2 * l],     hid[l + 64] * ow2[2 * l + 128]);
        else if (w == 1) acc = fmaf(hid[l], ow2[2 * l + 1], hid[l + 64] * ow2[2 * l + 129]);
        else             acc = fmaf(hid[128 + l], sw2[l],   hid[192 + l] * sw2[l + 64]);
        #pragma unroll
        for (int off = 32; off; off >>= 1) acc += __shfl_down(acc, off);
        if (l == 0) res[w] = acc + (w == 0 ? ob2[0] : (w == 1 ? ob2[1] : sb2[0]));
    }
    __syncthreads();
    if (t == 0) {
        int q = n & 63;
        int cpx = (int)(qb[2 * q + 0] * 128.0f);
        int cpy = (int)(qb[2 * q + 1] * 128.0f);
        int cpsx = (int)((float)cpx + res[0] * 8.0f);
        int cpsy = (int)((float)cpy + res[1] * 8.0f);
        RS[n] = cpsx - 8;
        CS[n] = cpsy - 8;
        SC[n] = res[2];
    }
}

__global__ __launch_bounds__(256) void k_scalemap(
    const int* __restrict__ RS, const int* __restrict__ CS, const float* __restrict__ SC,
    float* __restrict__ SMAP) {
    __shared__ int rs[64], cs[64];
    __shared__ float sc[64];
    int t = threadIdx.x;
    int p = blockIdx.x * 256 + t;
    int b = p >> 14;
    if (t < 64) { rs[t] = RS[b * 64 + t]; cs[t] = CS[b * 64 + t]; sc[t] = SC[b * 64 + t]; }
    __syncthreads();
    int off = p & (HW1 - 1);
    int r = off >> 7, c = off & 127;
    float sv = 1.0f;
    for (int q = 63; q >= 0; --q) {
        int r0 = rs[q], c0 = cs[q];
        if (r0 >= 0 && c0 >= 0 && (unsigned)(r - r0) < 16u && (unsigned)(c - c0) < 16u) {
            sv = sc[q]; break;
        }
    }
    SMAP[p] = sv;
}

// Persistent balanced k_out: 1024 blocks, each does exactly 3 tiles sharing
// (c_local, b): phase0 = direct ch (no LDS), phase1 = 2x up, phase2 = 4x up.
__global__ __launch_bounds__(256) void k_out(
    const float* __restrict__ a1, const float* __restrict__ a2, const float* __restrict__ a3,
    const float* __restrict__ n1, const float* __restrict__ n2, const float* __restrict__ n3,
    const float* __restrict__ SMAP, float* __restrict__ out) {
    __shared__ float cur[4096];
    __shared__ float nxt[4096];
    int t = threadIdx.x;
    int c_local = blockIdx.x >> 2;
    int b = blockIdx.x & 3;
    const f4* s4 = (const f4*)(SMAP + b * HW1);
    const size_t obase = (size_t)(b * 768) * HW1;

    // ---- phase 0: direct channel c_local ----
    {
        const f4* f  = (const f4*)(a1 + ((size_t)(b * 256 + c_local)) * HW1);
        const f4* fn = (const f4*)(n1 + ((size_t)(b * 256 + c_local)) * HW1);
        f4* o4 = (f4*)(out + obase + (size_t)c_local * HW1);
        for (int i = t; i < 4096; i += 256) {
            f4 fv = f[i];
            f4 sv = s4[i];
            f4 nv = __builtin_nontemporal_load(&fn[i]);
            f4 r;
            r.x = fmaf(fv.x, sv.x, nv.x);
            r.y = fmaf(fv.y, sv.y, nv.y);
            r.z = fmaf(fv.z, sv.z, nv.z);
            r.w = fmaf(fv.w, sv.w, nv.w);
            __builtin_nontemporal_store(r, &o4[i]);
        }
    }

    // ---- phase 1: 2x upsample channel 256 + c_local ----
    {
        const f4* s0 = (const f4*)(a2 + ((size_t)(b * 256 + c_local)) * HW2);
        const f4* s1 = (const f4*)(n2 + ((size_t)(b * 256 + c_local)) * HW2);
        f4* o4 = (f4*)(out + obase + (size_t)(256 + c_local) * HW1);
        for (int i = t; i < 1024; i += 256) {
            ((f4*)cur)[i] = s0[i];
            ((f4*)nxt)[i] = __builtin_nontemporal_load(&s1[i]);
        }
        __syncthreads();
        for (int i = t; i < 4096; i += 256) {
            int y = i >> 5, j = i & 31;
            int iy = (y - 1) >> 1;
            int y0 = max(iy, 0), y1 = min(iy + 1, 63);
            float wy = (y & 1) ? 0.25f : 0.75f;
            int cm1 = max(2 * j - 1, 0);
            int c0 = 2 * j, c1 = 2 * j + 1;
            int c2c = min(2 * j + 2, 63);
            const float* r0 = cur + y0 * 64; const float* r1 = cur + y1 * 64;
            const float* u0 = nxt + y0 * 64; const float* u1 = nxt + y1 * 64;
            float a0 = r0[cm1], a1v = r0[c0], a2v = r0[c1], a3v = r0[c2c];
            float b0 = r1[cm1], b1v = r1[c0], b2v = r1[c1], b3v = r1[c2c];
            float p0 = u0[cm1], p1 = u0[c0], p2 = u0[c1], p3 = u0[c2c];
            float q0 = u1[cm1], q1 = u1[c0], q2 = u1[c1], q3 = u1[c2c];
            float h0 = fmaf(0.25f, a0, 0.75f * a1v);
            float h1 = fmaf(0.75f, a1v, 0.25f * a2v);
            float h2 = fmaf(0.25f, a1v, 0.75f * a2v);
            float h3 = fmaf(0.75f, a2v, 0.25f * a3v);
            float g0 = fmaf(0.25f, b0, 0.75f * b1v);
            float g1 = fmaf(0.75f, b1v, 0.25f * b2v);
            float g2 = fmaf(0.25f, b1v, 0.75f * b2v);
            float g3 = fmaf(0.75f, b2v, 0.25f * b3v);
            float e0 = fmaf(0.25f, p0, 0.75f * p1);
            float e1 = fmaf(0.75f, p1, 0.25f * p2);
            float e2 = fmaf(0.25f, p1, 0.75f * p2);
            float e3 = fmaf(0.75f, p2, 0.25f * p3);
            float k0 = fmaf(0.25f, q0, 0.75f * q1);
            float k1 = fmaf(0.75f, q1, 0.25f * q2);
            float k2 = fmaf(0.25f, q1, 0.75f * q2);
            float k3 = fmaf(0.75f, q2, 0.25f * q3);
            f4 sv = s4[i];
            f4 r;
            r.x = fmaf(fmaf(g0 - h0, wy, h0), sv.x, fmaf(k0 - e0, wy, e0));
            r.y = fmaf(fmaf(g1 - h1, wy, h1), sv.y, fmaf(k1 - e1, wy, e1));
            r.z = fmaf(fmaf(g2 - h2, wy, h2), sv.z, fmaf(k2 - e2, wy, e2));
            r.w = fmaf(fmaf(g3 - h3, wy, h3), sv.w, fmaf(k3 - e3, wy, e3));
            __builtin_nontemporal_store(r, &o4[i]);
        }
    }

    __syncthreads();   // all reads of cur/nxt done before phase 2 restage

    // ---- phase 2: 4x upsample channel 512 + c_local ----
    {
        const f4* s0 = (const f4*)(a3 + ((size_t)(b * 256 + c_local)) * HW3);
        const f4* s1 = (const f4*)(n3 + ((size_t)(b * 256 + c_local)) * HW3);
        f4* o4 = (f4*)(out + obase + (size_t)(512 + c_local) * HW1);
        for (int i = t; i < 256; i += 256) {
            ((f4*)cur)[i] = s0[i];
            ((f4*)nxt)[i] = __builtin_nontemporal_load(&s1[i]);
        }
        __syncthreads();
        for (int i = t; i < 4096; i += 256) {
            int y = i >> 5, j = i & 31;
            int iy = (y - 2) >> 2;
            int y0 = max(iy, 0), y1 = min(iy + 1, 31);
            int ym = y & 3;
            float wy = (ym < 2) ? (0.625f + 0.25f * ym) : (0.25f * ym - 0.375f);
            int cm1 = max(j - 1, 0);
            int c0 = j, c1 = min(j + 1, 31);
            const float* r0 = cur + y0 * 32; const float* r1 = cur + y1 * 32;
            const float* u0 = nxt + y0 * 32; const float* u1 = nxt + y1 * 32;
            float a0 = r0[cm1], a1v = r0[c0], a2v = r0[c1];
            float b0 = r1[cm1], b1v = r1[c0], b2v = r1[c1];
            float p0 = u0[cm1], p1 = u0[c0], p2 = u0[c1];
            float q0 = u1[cm1], q1 = u1[c0], q2 = u1[c1];
            float h0 = fmaf(0.375f, a0, 0.625f * a1v);
            float h1 = fmaf(0.125f, a0, 0.875f * a1v);
            float h2 = fmaf(0.875f, a1v, 0.125f * a2v);
            float h3 = fmaf(0.625f, a1v, 0.375f * a2v);
            float g0 = fmaf(0.375f, b0, 0.625f * b1v);
            float g1 = fmaf(0.125f, b0, 0.875f * b1v);
            float g2 = fmaf(0.875f, b1v, 0.125f * b2v);
            float g3 = fmaf(0.625f, b1v, 0.375f * b2v);
            float e0 = fmaf(0.375f, p0, 0.625f * p1);
            float e1 = fmaf(0.125f, p0, 0.875f * p1);
            float e2 = fmaf(0.875f, p1, 0.125f * p2);
            float e3 = fmaf(0.625f, p1, 0.375f * p2);
            float k0 = fmaf(0.375f, q0, 0.625f * q1);
            float k1 = fmaf(0.125f, q0, 0.875f * q1);
            float k2 = fmaf(0.875f, q1, 0.125f * q2);
            float k3 = fmaf(0.625f, q1, 0.375f * q2);
            f4 sv = s4[i];
            f4 r;
            r.x = fmaf(fmaf(g0 - h0, wy, h0), sv.x, fmaf(k0 - e0, wy, e0));
            r.y = fmaf(fmaf(g1 - h1, wy, h1), sv.y, fmaf(k1 - e1, wy, e1));
            r.z = fmaf(fmaf(g2 - h2, wy, h2), sv.z, fmaf(k2 - e2, wy, e2));
            r.w = fmaf(fmaf(g3 - h3, wy, h3), sv.w, fmaf(k3 - e3, wy, e3));
            __builtin_nontemporal_store(r, &o4[i]);
        }
    }
}

extern "C" void kernel_launch(void* const* d_in, const int* in_sizes, int n_in,
                              void* d_out, int out_size, void* d_ws, size_t ws_size,
                              hipStream_t stream) {
    (void)in_sizes; (void)n_in; (void)out_size; (void)ws_size;
    const float* t0_l1 = (const float*)d_in[1];
    const float* t0_l2 = (const float*)d_in[2];
    const float* t0_l3 = (const float*)d_in[3];
    const float* t1_l1 = (const float*)d_in[5];
    const float* t1_l2 = (const float*)d_in[6];
    const float* t1_l3 = (const float*)d_in[7];
    const float* qb    = (const float*)d_in[8];
    const float* ow1   = (const float*)d_in[9];
    const float* ob1   = (const float*)d_in[10];
    const float* ow2   = (const float*)d_in[11];
    const float* ob2   = (const float*)d_in[12];
    const float* sw1   = (const float*)d_in[13];
    const float* sb1   = (const float*)d_in[14];
    const float* sw2   = (const float*)d_in[15];
    const float* sb2   = (const float*)d_in[16];

    char* ws = (char*)d_ws;
    float* SUM1 = (float*)(ws + 0);
    float* S2   = (float*)(ws + 262144);
    float* S3   = (float*)(ws + 327680);
    int*   RS   = (int*)  (ws + 344064);
    int*   CS   = (int*)  (ws + 345088);
    float* SC   = (float*)(ws + 346112);
    float* SMAP = (float*)(ws + 347136);
    float* out  = (float*)d_out;

    hipLaunchKernelGGL(k_sums, dim3(672), dim3(256), 0, stream,
                       t0_l1, t0_l2, t0_l3, SUM1, S2, S3);
    hipLaunchKernelGGL(k_query, dim3(256), dim3(256), 0, stream,
                       SUM1, S2, S3, qb, ow1, ob1, ow2, ob2, sw1, sb1, sw2, sb2, RS, CS, SC);
    hipLaunchKernelGGL(k_scalemap, dim3(256), dim3(256), 0, stream, RS, CS, SC, SMAP);
    hipLaunchKernelGGL(k_out, dim3(1024), dim3(256), 0, stream,
                       t0_l1, t0_l2, t0_l3, t1_l1, t1_l2, t1_l3, SMAP, out);
}